// Round 6
// baseline (826.563 us; speedup 1.0000x reference)
//
#include <hip/hip_runtime.h>

#define N_NODES 100000
#define F_IN 128
#define F_HID 32
#define BN 128                  // nodes per bucket (pow2)
#define NBUCK 782               // ceil(100000/128)
#define NBLK 512                // edge partition chunks

// ---------------- phase A: bucket partition of edges (no global atomics) ----------------

__global__ __launch_bounds__(256) void part_count(const int* __restrict__ src,
                                                  const int* __restrict__ dst, int E,
                                                  unsigned* __restrict__ cntD,
                                                  unsigned* __restrict__ cntS) {
    __shared__ unsigned cd[NBUCK], cs[NBUCK];
    for (int i = threadIdx.x; i < NBUCK; i += 256) { cd[i] = 0; cs[i] = 0; }
    __syncthreads();
    int chunk = (E + NBLK - 1) / NBLK;
    int e0 = blockIdx.x * chunk, e1 = min(E, e0 + chunk);
    for (int e = e0 + threadIdx.x; e < e1; e += 256) {
        atomicAdd(&cd[((unsigned)dst[e]) >> 7], 1u);   // LDS atomic
        atomicAdd(&cs[((unsigned)src[e]) >> 7], 1u);
    }
    __syncthreads();
    unsigned* od = cntD + (size_t)blockIdx.x * NBUCK;
    unsigned* os = cntS + (size_t)blockIdx.x * NBUCK;
    for (int i = threadIdx.x; i < NBUCK; i += 256) { od[i] = cd[i]; os[i] = cs[i]; }
}

// per-bucket exclusive scan over blocks (in place); totals[k] = bucket size
__global__ __launch_bounds__(512) void col_scan(unsigned* __restrict__ cnt,
                                                unsigned* __restrict__ totals) {
    __shared__ unsigned buf[2][512];
    int k = blockIdx.x, t = threadIdx.x;
    unsigned v = cnt[(size_t)t * NBUCK + k];
    buf[0][t] = v;
    __syncthreads();
    int cur = 0;
    for (int off = 1; off < 512; off <<= 1) {
        unsigned x = buf[cur][t];
        if (t >= off) x += buf[cur][t - off];
        buf[cur ^ 1][t] = x;
        cur ^= 1;
        __syncthreads();
    }
    cnt[(size_t)t * NBUCK + k] = buf[cur][t] - v;  // exclusive over blocks
    if (t == 511) totals[k] = buf[cur][511];
}

// exclusive scan of bucket totals -> start[0..NBUCK] (start[NBUCK] = E)
__global__ __launch_bounds__(1024) void total_scan(const unsigned* __restrict__ totals,
                                                   unsigned* __restrict__ start) {
    __shared__ unsigned buf[2][1024];
    int t = threadIdx.x;
    buf[0][t] = (t < NBUCK) ? totals[t] : 0;
    __syncthreads();
    int cur = 0;
    for (int off = 1; off < 1024; off <<= 1) {
        unsigned x = buf[cur][t];
        if (t >= off) x += buf[cur][t - off];
        buf[cur ^ 1][t] = x;
        cur ^= 1;
        __syncthreads();
    }
    if (t < NBUCK) start[t + 1] = buf[cur][t];
    if (t == 0) start[0] = 0;
}

// scatter edges into bucket-partitioned layout; slots disjoint by construction
__global__ __launch_bounds__(256) void part_scatter(const int* __restrict__ src,
                                                    const int* __restrict__ dst, int E,
                                                    const unsigned* __restrict__ cntD,
                                                    const unsigned* __restrict__ cntS,
                                                    const unsigned* __restrict__ startD,
                                                    const unsigned* __restrict__ startS,
                                                    unsigned* __restrict__ pairD,
                                                    unsigned* __restrict__ valS) {
    __shared__ unsigned curD[NBUCK], curS[NBUCK];
    for (int i = threadIdx.x; i < NBUCK; i += 256) { curD[i] = 0; curS[i] = 0; }
    __syncthreads();
    int chunk = (E + NBLK - 1) / NBLK;
    int e0 = blockIdx.x * chunk, e1 = min(E, e0 + chunk);
    const unsigned* bd = cntD + (size_t)blockIdx.x * NBUCK;
    const unsigned* bs = cntS + (size_t)blockIdx.x * NBUCK;
    for (int e = e0 + threadIdx.x; e < e1; e += 256) {
        unsigned s = (unsigned)src[e], d = (unsigned)dst[e];
        unsigned kd = d >> 7, ks = s >> 7;
        unsigned rd = atomicAdd(&curD[kd], 1u);                 // LDS rank
        pairD[startD[kd] + bd[kd] + rd] = s | ((d & 127u) << 17);
        unsigned rs = atomicAdd(&curS[ks], 1u);
        valS[startS[ks] + bs[ks] + rs] = s & 127u;
    }
}

// per-bucket LDS degree count -> norms (D side: norm_in, S side: norm_out)
__global__ __launch_bounds__(256) void bucket_norms(const unsigned* __restrict__ pairD,
                                                    const unsigned* __restrict__ startD,
                                                    const unsigned* __restrict__ valS,
                                                    const unsigned* __restrict__ startS,
                                                    float* __restrict__ norm_in,
                                                    float* __restrict__ norm_out, int n) {
    __shared__ unsigned cnt[BN];
    for (int i = threadIdx.x; i < BN; i += 256) cnt[i] = 0;
    __syncthreads();
    int b = blockIdx.x;
    if (b < NBUCK) {
        unsigned a0 = startD[b], a1 = startD[b + 1];
        for (unsigned i = a0 + threadIdx.x; i < a1; i += 256)
            atomicAdd(&cnt[(pairD[i] >> 17) & 127u], 1u);
        __syncthreads();
        for (int l = threadIdx.x; l < BN; l += 256) {
            int node = b * BN + l;
            if (node < n) {
                unsigned c = cnt[l];
                norm_in[node] = rsqrtf((float)(c > 1u ? c : 1u));
            }
        }
    } else {
        int k = b - NBUCK;
        unsigned a0 = startS[k], a1 = startS[k + 1];
        for (unsigned i = a0 + threadIdx.x; i < a1; i += 256)
            atomicAdd(&cnt[valS[i]], 1u);
        __syncthreads();
        for (int l = threadIdx.x; l < BN; l += 256) {
            int node = k * BN + l;
            if (node < n) {
                unsigned c = cnt[l];
                norm_out[node] = rsqrtf((float)(c > 1u ? c : 1u));
            }
        }
    }
}

// ---------------- layer-1 projection with norm_out prescale ----------------

__global__ void gemm1_kernel(const float* __restrict__ x, const float* __restrict__ W,
                             const float* __restrict__ norm_out, float* __restrict__ h, int n) {
    __shared__ float Wl[F_IN * F_HID];  // 16 KB
    for (int i = threadIdx.x; i < F_IN * F_HID; i += blockDim.x) Wl[i] = W[i];
    __syncthreads();
    int node = blockIdx.x * blockDim.x + threadIdx.x;
    if (node >= n) return;
    float acc[F_HID];
#pragma unroll
    for (int j = 0; j < F_HID; ++j) acc[j] = 0.f;
    const float4* row = reinterpret_cast<const float4*>(x + (size_t)node * F_IN);
#pragma unroll 2
    for (int k4 = 0; k4 < F_IN / 4; ++k4) {
        float4 v = row[k4];
        const float* w0 = &Wl[(k4 * 4 + 0) * F_HID];
        const float* w1 = &Wl[(k4 * 4 + 1) * F_HID];
        const float* w2 = &Wl[(k4 * 4 + 2) * F_HID];
        const float* w3 = &Wl[(k4 * 4 + 3) * F_HID];
#pragma unroll
        for (int j = 0; j < F_HID; ++j)
            acc[j] += v.x * w0[j] + v.y * w1[j] + v.z * w2[j] + v.w * w3[j];
    }
    float s = norm_out[node];
    float* out = h + (size_t)node * F_HID;
#pragma unroll
    for (int j = 0; j < F_HID; ++j) out[j] = acc[j] * s;
}

// ---------------- bucketed aggregation: LDS accumulate, no CSR ----------------

// layer 1: agg + norm_in + b1 + relu, then GEMM2 via shuffle, prescale norm_out -> h2s
__global__ __launch_bounds__(512) void agg1_bucket(const float* __restrict__ h1s,
                                                   const unsigned* __restrict__ pairD,
                                                   const unsigned* __restrict__ startD,
                                                   const float* __restrict__ norm_in,
                                                   const float* __restrict__ norm_out,
                                                   const float* __restrict__ b1,
                                                   const float* __restrict__ W2,
                                                   float* __restrict__ h2s, int n) {
    __shared__ float acc[BN][F_HID];     // 16 KB
    __shared__ float W2l[F_HID * F_HID]; // 4 KB
    for (int i = threadIdx.x; i < BN * F_HID; i += 512) ((float*)acc)[i] = 0.f;
    for (int i = threadIdx.x; i < F_HID * F_HID; i += 512) W2l[i] = W2[i];
    __syncthreads();
    int k = blockIdx.x;
    unsigned a0 = startD[k], a1 = startD[k + 1];
    int f = threadIdx.x & 31;
    int grp = threadIdx.x >> 5;  // 16 groups of 32
    for (unsigned i = a0 + grp; i < a1; i += 16) {
        unsigned v = pairD[i];
        unsigned s = v & 0x1FFFFu;
        unsigned l = (v >> 17) & 127u;
        atomicAdd(&acc[l][f], h1s[(size_t)s * F_HID + f]);  // LDS f32 atomic, 2-way banks
    }
    __syncthreads();
    for (int l = grp; l < BN; l += 16) {
        int node = k * BN + l;
        if (node < n) {
            float t = acc[l][f] * norm_in[node] + b1[f];
            t = t > 0.f ? t : 0.f;
            float o = 0.f;
#pragma unroll
            for (int kk = 0; kk < F_HID; ++kk) o += __shfl(t, kk, 32) * W2l[kk * F_HID + f];
            h2s[(size_t)node * F_HID + f] = o * norm_out[node];
        }
    }
}

// layer 2: agg + norm_in + b2 -> out
__global__ __launch_bounds__(512) void agg2_bucket(const float* __restrict__ h2s,
                                                   const unsigned* __restrict__ pairD,
                                                   const unsigned* __restrict__ startD,
                                                   const float* __restrict__ norm_in,
                                                   const float* __restrict__ b2,
                                                   float* __restrict__ out, int n) {
    __shared__ float acc[BN][F_HID];
    for (int i = threadIdx.x; i < BN * F_HID; i += 512) ((float*)acc)[i] = 0.f;
    __syncthreads();
    int k = blockIdx.x;
    unsigned a0 = startD[k], a1 = startD[k + 1];
    int f = threadIdx.x & 31;
    int grp = threadIdx.x >> 5;
    for (unsigned i = a0 + grp; i < a1; i += 16) {
        unsigned v = pairD[i];
        unsigned s = v & 0x1FFFFu;
        unsigned l = (v >> 17) & 127u;
        atomicAdd(&acc[l][f], h2s[(size_t)s * F_HID + f]);
    }
    __syncthreads();
    for (int l = grp; l < BN; l += 16) {
        int node = k * BN + l;
        if (node < n)
            out[(size_t)node * F_HID + f] = acc[l][f] * norm_in[node] + b2[f];
    }
}

// ---------------- launch ----------------

static inline size_t align256(size_t x) { return (x + 255) & ~(size_t)255; }

extern "C" void kernel_launch(void* const* d_in, const int* in_sizes, int n_in,
                              void* d_out, int out_size, void* d_ws, size_t ws_size,
                              hipStream_t stream) {
    const float* features = (const float*)d_in[0];
    const float* W1 = (const float*)d_in[1];
    const float* b1 = (const float*)d_in[2];
    const float* W2 = (const float*)d_in[3];
    const float* b2 = (const float*)d_in[4];
    const int* src = (const int*)d_in[5];
    const int* dst = (const int*)d_in[6];
    const int E = in_sizes[5];
    const int n = N_NODES;
    float* out = (float*)d_out;

    char* ws = (char*)d_ws;
    size_t off = 0;
    float* norm_out = (float*)(ws + off); off += align256((size_t)n * 4);
    float* norm_in = (float*)(ws + off);  off += align256((size_t)n * 4);
    unsigned* startD = (unsigned*)(ws + off); off += align256((NBUCK + 1) * 4);
    unsigned* startS = (unsigned*)(ws + off); off += align256((NBUCK + 1) * 4);
    unsigned* totD = (unsigned*)(ws + off);   off += align256(NBUCK * 4);
    unsigned* totS = (unsigned*)(ws + off);   off += align256(NBUCK * 4);
    unsigned* pairD = (unsigned*)(ws + off);  off += align256((size_t)E * 4);  // 6.4 MB
    unsigned* valS = (unsigned*)(ws + off);   off += align256((size_t)E * 4);  // 6.4 MB
    // h1s region aliases the count matrices (cnt dead after part_scatter, h1s born at gemm1)
    size_t regA = off;
    unsigned* cntD = (unsigned*)(ws + regA);                                   // 1.6 MB
    unsigned* cntS = (unsigned*)(ws + regA + (size_t)NBLK * NBUCK * 4);        // 1.6 MB
    float* h1s = (float*)(ws + regA);                                          // 12.8 MB
    float* h2s = (float*)(ws + regA + (size_t)n * F_HID * 4);                  // 12.8 MB

    // phase A: partition edges by dst-bucket (pairs) and src-bucket (locals)
    part_count<<<NBLK, 256, 0, stream>>>(src, dst, E, cntD, cntS);
    col_scan<<<NBUCK, 512, 0, stream>>>(cntD, totD);
    col_scan<<<NBUCK, 512, 0, stream>>>(cntS, totS);
    total_scan<<<1, 1024, 0, stream>>>(totD, startD);
    total_scan<<<1, 1024, 0, stream>>>(totS, startS);
    part_scatter<<<NBLK, 256, 0, stream>>>(src, dst, E, cntD, cntS, startD, startS, pairD, valS);

    // norms from partitioned data (per-bucket LDS counts)
    bucket_norms<<<2 * NBUCK, 256, 0, stream>>>(pairD, startD, valS, startS, norm_in, norm_out, n);

    // layer 1 projection (+ norm_out prescale)
    gemm1_kernel<<<(n + 255) / 256, 256, 0, stream>>>(features, W1, norm_out, h1s, n);

    // bucketed aggregation, fused epilogues
    agg1_bucket<<<NBUCK, 512, 0, stream>>>(h1s, pairD, startD, norm_in, norm_out, b1, W2, h2s, n);
    agg2_bucket<<<NBUCK, 512, 0, stream>>>(h2s, pairD, startD, norm_in, b2, out, n);
}

// Round 7
// 242.183 us; speedup vs baseline: 3.4130x; 3.4130x over previous
//
#include <hip/hip_runtime.h>

#define N_NODES 100000
#define F_IN 128
#define F_HID 32
#define BN 128                  // nodes per bucket (pow2)
#define NBUCK 782               // ceil(100000/128)
#define NBLK 512                // edge partition chunks

// ---------------- phase A: bucket partition of edges (no global atomics) ----------------

__global__ __launch_bounds__(256) void part_count(const int* __restrict__ src,
                                                  const int* __restrict__ dst, int E,
                                                  unsigned* __restrict__ cntD,
                                                  unsigned* __restrict__ cntS) {
    __shared__ unsigned cd[NBUCK], cs[NBUCK];
    for (int i = threadIdx.x; i < NBUCK; i += 256) { cd[i] = 0; cs[i] = 0; }
    __syncthreads();
    int chunk = (E + NBLK - 1) / NBLK;
    int e0 = blockIdx.x * chunk, e1 = min(E, e0 + chunk);
    for (int e = e0 + threadIdx.x; e < e1; e += 256) {
        atomicAdd(&cd[((unsigned)dst[e]) >> 7], 1u);   // LDS atomic
        atomicAdd(&cs[((unsigned)src[e]) >> 7], 1u);
    }
    __syncthreads();
    unsigned* od = cntD + (size_t)blockIdx.x * NBUCK;
    unsigned* os = cntS + (size_t)blockIdx.x * NBUCK;
    for (int i = threadIdx.x; i < NBUCK; i += 256) { od[i] = cd[i]; os[i] = cs[i]; }
}

// per-bucket exclusive scan over blocks (in place); totals[k] = bucket size
__global__ __launch_bounds__(512) void col_scan(unsigned* __restrict__ cnt,
                                                unsigned* __restrict__ totals) {
    __shared__ unsigned buf[2][512];
    int k = blockIdx.x, t = threadIdx.x;
    unsigned v = cnt[(size_t)t * NBUCK + k];
    buf[0][t] = v;
    __syncthreads();
    int cur = 0;
    for (int off = 1; off < 512; off <<= 1) {
        unsigned x = buf[cur][t];
        if (t >= off) x += buf[cur][t - off];
        buf[cur ^ 1][t] = x;
        cur ^= 1;
        __syncthreads();
    }
    cnt[(size_t)t * NBUCK + k] = buf[cur][t] - v;  // exclusive over blocks
    if (t == 511) totals[k] = buf[cur][511];
}

// exclusive scan of bucket totals -> start[0..NBUCK] (start[NBUCK] = E)
__global__ __launch_bounds__(1024) void total_scan(const unsigned* __restrict__ totals,
                                                   unsigned* __restrict__ start) {
    __shared__ unsigned buf[2][1024];
    int t = threadIdx.x;
    buf[0][t] = (t < NBUCK) ? totals[t] : 0;
    __syncthreads();
    int cur = 0;
    for (int off = 1; off < 1024; off <<= 1) {
        unsigned x = buf[cur][t];
        if (t >= off) x += buf[cur][t - off];
        buf[cur ^ 1][t] = x;
        cur ^= 1;
        __syncthreads();
    }
    if (t < NBUCK) start[t + 1] = buf[cur][t];
    if (t == 0) start[0] = 0;
}

// scatter edges into bucket-partitioned layout; slots disjoint by construction
__global__ __launch_bounds__(256) void part_scatter(const int* __restrict__ src,
                                                    const int* __restrict__ dst, int E,
                                                    const unsigned* __restrict__ cntD,
                                                    const unsigned* __restrict__ cntS,
                                                    const unsigned* __restrict__ startD,
                                                    const unsigned* __restrict__ startS,
                                                    unsigned* __restrict__ pairD,
                                                    unsigned* __restrict__ valS) {
    __shared__ unsigned curD[NBUCK], curS[NBUCK];
    for (int i = threadIdx.x; i < NBUCK; i += 256) { curD[i] = 0; curS[i] = 0; }
    __syncthreads();
    int chunk = (E + NBLK - 1) / NBLK;
    int e0 = blockIdx.x * chunk, e1 = min(E, e0 + chunk);
    const unsigned* bd = cntD + (size_t)blockIdx.x * NBUCK;
    const unsigned* bs = cntS + (size_t)blockIdx.x * NBUCK;
    for (int e = e0 + threadIdx.x; e < e1; e += 256) {
        unsigned s = (unsigned)src[e], d = (unsigned)dst[e];
        unsigned kd = d >> 7, ks = s >> 7;
        unsigned rd = atomicAdd(&curD[kd], 1u);                 // LDS rank
        pairD[startD[kd] + bd[kd] + rd] = s | ((d & 127u) << 17);
        unsigned rs = atomicAdd(&curS[ks], 1u);
        valS[startS[ks] + bs[ks] + rs] = s & 127u;
    }
}

// ---------------- phase B: per-bucket counting sort -> full CSR (no global atomics) ----------

__global__ __launch_bounds__(256) void bucket_sort(const unsigned* __restrict__ pairD,
                                                   const unsigned* __restrict__ startD,
                                                   int* __restrict__ col, int* __restrict__ row_ptr,
                                                   int* __restrict__ deg_arr,
                                                   float* __restrict__ norm_in, int n) {
    __shared__ unsigned cnt[BN];
    __shared__ unsigned base[BN];
    __shared__ unsigned sbuf[2][BN];
    int t = threadIdx.x;
    if (t < BN) cnt[t] = 0;
    __syncthreads();
    int k = blockIdx.x;
    unsigned a0 = startD[k], a1 = startD[k + 1];
    for (unsigned i = a0 + t; i < a1; i += 256)
        atomicAdd(&cnt[(pairD[i] >> 17) & 127u], 1u);
    __syncthreads();
    unsigned v = (t < BN) ? cnt[t] : 0;
    if (t < BN) sbuf[0][t] = v;
    __syncthreads();
    int cur = 0;
    for (int off = 1; off < BN; off <<= 1) {
        if (t < BN) {
            unsigned x = sbuf[cur][t];
            if (t >= off) x += sbuf[cur][t - off];
            sbuf[cur ^ 1][t] = x;
        }
        cur ^= 1;
        __syncthreads();
    }
    if (t < BN) {
        base[t] = a0 + sbuf[cur][t] - v;  // exclusive within bucket
        int node = k * BN + t;
        if (node < n) {
            row_ptr[node] = (int)base[t];
            deg_arr[node] = (int)v;
            norm_in[node] = rsqrtf((float)(v > 1u ? v : 1u));
        }
        cnt[t] = 0;  // reuse as cursor
    }
    __syncthreads();
    for (unsigned i = a0 + t; i < a1; i += 256) {
        unsigned pv = pairD[i];
        unsigned l = (pv >> 17) & 127u;
        unsigned r = atomicAdd(&cnt[l], 1u);   // LDS rank
        col[base[l] + r] = (int)(pv & 0x1FFFFu);
    }
}

// src-side degree -> norm_out
__global__ __launch_bounds__(256) void bucket_norms_src(const unsigned* __restrict__ valS,
                                                        const unsigned* __restrict__ startS,
                                                        float* __restrict__ norm_out, int n) {
    __shared__ unsigned cnt[BN];
    if (threadIdx.x < BN) cnt[threadIdx.x] = 0;
    __syncthreads();
    int k = blockIdx.x;
    unsigned a0 = startS[k], a1 = startS[k + 1];
    for (unsigned i = a0 + threadIdx.x; i < a1; i += 256)
        atomicAdd(&cnt[valS[i]], 1u);
    __syncthreads();
    if (threadIdx.x < BN) {
        int node = k * BN + threadIdx.x;
        if (node < n) {
            unsigned c = cnt[threadIdx.x];
            norm_out[node] = rsqrtf((float)(c > 1u ? c : 1u));
        }
    }
}

// ---------------- layer-1 projection with norm_out prescale ----------------

__global__ void gemm1_kernel(const float* __restrict__ x, const float* __restrict__ W,
                             const float* __restrict__ norm_out, float* __restrict__ h, int n) {
    __shared__ float Wl[F_IN * F_HID];  // 16 KB
    for (int i = threadIdx.x; i < F_IN * F_HID; i += blockDim.x) Wl[i] = W[i];
    __syncthreads();
    int node = blockIdx.x * blockDim.x + threadIdx.x;
    if (node >= n) return;
    float acc[F_HID];
#pragma unroll
    for (int j = 0; j < F_HID; ++j) acc[j] = 0.f;
    const float4* row = reinterpret_cast<const float4*>(x + (size_t)node * F_IN);
#pragma unroll 2
    for (int k4 = 0; k4 < F_IN / 4; ++k4) {
        float4 v = row[k4];
        const float* w0 = &Wl[(k4 * 4 + 0) * F_HID];
        const float* w1 = &Wl[(k4 * 4 + 1) * F_HID];
        const float* w2 = &Wl[(k4 * 4 + 2) * F_HID];
        const float* w3 = &Wl[(k4 * 4 + 3) * F_HID];
#pragma unroll
        for (int j = 0; j < F_HID; ++j)
            acc[j] += v.x * w0[j] + v.y * w1[j] + v.z * w2[j] + v.w * w3[j];
    }
    float s = norm_out[node];
    float* out = h + (size_t)node * F_HID;
#pragma unroll
    for (int j = 0; j < F_HID; ++j) out[j] = acc[j] * s;
}

// ---------------- gather aggregation (warp per node, zero atomics) ----------------

__global__ __launch_bounds__(256) void agg1_kernel(const float* __restrict__ h1s,
                                                   const int* __restrict__ row_ptr,
                                                   const int* __restrict__ deg_arr,
                                                   const int* __restrict__ col,
                                                   const float* __restrict__ norm_in,
                                                   const float* __restrict__ norm_out,
                                                   const float* __restrict__ b1,
                                                   const float* __restrict__ W2,
                                                   float* __restrict__ h2s, int n) {
    __shared__ float W2l[F_HID * F_HID];
    for (int i = threadIdx.x; i < F_HID * F_HID; i += blockDim.x) W2l[i] = W2[i];
    __syncthreads();
    int lane = threadIdx.x & 31;
    int node = blockIdx.x * (blockDim.x >> 5) + (threadIdx.x >> 5);
    if (node >= n) return;
    int start = row_ptr[node];
    int deg = deg_arr[node];
    float acc0 = 0.f, acc1 = 0.f;
    int j = 0;
    for (; j + 1 < deg; j += 2) {
        int s0 = col[start + j];
        int s1 = col[start + j + 1];
        acc0 += h1s[(size_t)s0 * F_HID + lane];
        acc1 += h1s[(size_t)s1 * F_HID + lane];
    }
    if (j < deg) acc0 += h1s[(size_t)col[start + j] * F_HID + lane];
    float t = (acc0 + acc1) * norm_in[node] + b1[lane];
    t = t > 0.f ? t : 0.f;
    float o = 0.f;
#pragma unroll
    for (int k = 0; k < F_HID; ++k) {
        float tk = __shfl(t, k, 32);
        o += tk * W2l[k * F_HID + lane];
    }
    h2s[(size_t)node * F_HID + lane] = o * norm_out[node];
}

__global__ __launch_bounds__(256) void agg2_kernel(const float* __restrict__ h2s,
                                                   const int* __restrict__ row_ptr,
                                                   const int* __restrict__ deg_arr,
                                                   const int* __restrict__ col,
                                                   const float* __restrict__ norm_in,
                                                   const float* __restrict__ b2,
                                                   float* __restrict__ out, int n) {
    int lane = threadIdx.x & 31;
    int node = blockIdx.x * (blockDim.x >> 5) + (threadIdx.x >> 5);
    if (node >= n) return;
    int start = row_ptr[node];
    int deg = deg_arr[node];
    float acc0 = 0.f, acc1 = 0.f;
    int j = 0;
    for (; j + 1 < deg; j += 2) {
        int s0 = col[start + j];
        int s1 = col[start + j + 1];
        acc0 += h2s[(size_t)s0 * F_HID + lane];
        acc1 += h2s[(size_t)s1 * F_HID + lane];
    }
    if (j < deg) acc0 += h2s[(size_t)col[start + j] * F_HID + lane];
    out[(size_t)node * F_HID + lane] = (acc0 + acc1) * norm_in[node] + b2[lane];
}

// ---------------- launch ----------------

static inline size_t align256(size_t x) { return (x + 255) & ~(size_t)255; }

extern "C" void kernel_launch(void* const* d_in, const int* in_sizes, int n_in,
                              void* d_out, int out_size, void* d_ws, size_t ws_size,
                              hipStream_t stream) {
    const float* features = (const float*)d_in[0];
    const float* W1 = (const float*)d_in[1];
    const float* b1 = (const float*)d_in[2];
    const float* W2 = (const float*)d_in[3];
    const float* b2 = (const float*)d_in[4];
    const int* src = (const int*)d_in[5];
    const int* dst = (const int*)d_in[6];
    const int E = in_sizes[5];
    const int n = N_NODES;
    float* out = (float*)d_out;

    char* ws = (char*)d_ws;
    size_t off = 0;
    float* norm_out = (float*)(ws + off); off += align256((size_t)n * 4);
    float* norm_in = (float*)(ws + off);  off += align256((size_t)n * 4);
    int* row_ptr = (int*)(ws + off);      off += align256((size_t)n * 4);
    int* deg_arr = (int*)(ws + off);      off += align256((size_t)n * 4);
    unsigned* startD = (unsigned*)(ws + off); off += align256((NBUCK + 1) * 4);
    unsigned* startS = (unsigned*)(ws + off); off += align256((NBUCK + 1) * 4);
    unsigned* totD = (unsigned*)(ws + off);   off += align256(NBUCK * 4);
    unsigned* totS = (unsigned*)(ws + off);   off += align256(NBUCK * 4);
    int* col = (int*)(ws + off);              off += align256((size_t)E * 4);  // 6.4 MB

    // region X: pairD+valS (live: part_scatter -> bucket kernels) then h2s (live: agg1 -> agg2)
    size_t regX = off;
    unsigned* pairD = (unsigned*)(ws + regX);                        // 6.4 MB
    unsigned* valS = (unsigned*)(ws + regX + (size_t)E * 4);         // 6.4 MB
    float* h2s = (float*)(ws + regX);                                // 12.8 MB
    off += align256((size_t)2 * E * 4);
    // region Y: cntD+cntS (live: part_count -> part_scatter) then h1s (live: gemm1 -> agg1)
    size_t regY = off;
    unsigned* cntD = (unsigned*)(ws + regY);                         // 1.6 MB
    unsigned* cntS = (unsigned*)(ws + regY + (size_t)NBLK * NBUCK * 4);
    float* h1s = (float*)(ws + regY);                                // 12.8 MB

    // phase A: partition edges by dst-bucket (pairs) and src-bucket (locals)
    part_count<<<NBLK, 256, 0, stream>>>(src, dst, E, cntD, cntS);
    col_scan<<<NBUCK, 512, 0, stream>>>(cntD, totD);
    col_scan<<<NBUCK, 512, 0, stream>>>(cntS, totS);
    total_scan<<<1, 1024, 0, stream>>>(totD, startD);
    total_scan<<<1, 1024, 0, stream>>>(totS, startS);
    part_scatter<<<NBLK, 256, 0, stream>>>(src, dst, E, cntD, cntS, startD, startS, pairD, valS);

    // phase B: per-bucket counting sort -> CSR (+ norm_in), src norms
    bucket_sort<<<NBUCK, 256, 0, stream>>>(pairD, startD, col, row_ptr, deg_arr, norm_in, n);
    bucket_norms_src<<<NBUCK, 256, 0, stream>>>(valS, startS, norm_out, n);

    // layer 1 projection (+ norm_out prescale)
    gemm1_kernel<<<(n + 255) / 256, 256, 0, stream>>>(features, W1, norm_out, h1s, n);

    // gather aggregation, fused epilogues
    agg1_kernel<<<(n + 7) / 8, 256, 0, stream>>>(h1s, row_ptr, deg_arr, col, norm_in,
                                                 norm_out, b1, W2, h2s, n);
    agg2_kernel<<<(n + 7) / 8, 256, 0, stream>>>(h2s, row_ptr, deg_arr, col, norm_in, b2, out, n);
}

// Round 8
// 187.606 us; speedup vs baseline: 4.4058x; 1.2909x over previous
//
#include <hip/hip_runtime.h>

#define N_NODES 100000
#define F_IN 128
#define F_HID 32
#define BN 128                  // nodes per bucket (pow2)
#define NBUCK 782               // ceil(100000/128)
#define NBLK 512                // edge partition chunks

// ---------------- phase A: bucket partition of edges (no global atomics) ----------------

__global__ __launch_bounds__(256) void part_count(const int* __restrict__ src,
                                                  const int* __restrict__ dst, int E,
                                                  unsigned* __restrict__ cntD,
                                                  unsigned* __restrict__ cntS) {
    __shared__ unsigned cd[NBUCK], cs[NBUCK];
    for (int i = threadIdx.x; i < NBUCK; i += 256) { cd[i] = 0; cs[i] = 0; }
    __syncthreads();
    int chunk = (E + NBLK - 1) / NBLK;
    int e0 = blockIdx.x * chunk, e1 = min(E, e0 + chunk);
    for (int e = e0 + threadIdx.x; e < e1; e += 256) {
        atomicAdd(&cd[((unsigned)dst[e]) >> 7], 1u);   // LDS atomic
        atomicAdd(&cs[((unsigned)src[e]) >> 7], 1u);
    }
    __syncthreads();
    unsigned* od = cntD + (size_t)blockIdx.x * NBUCK;
    unsigned* os = cntS + (size_t)blockIdx.x * NBUCK;
    for (int i = threadIdx.x; i < NBUCK; i += 256) { od[i] = cd[i]; os[i] = cs[i]; }
}

// per-bucket exclusive scan over blocks (in place); totals[k] = bucket size
__global__ __launch_bounds__(512) void col_scan(unsigned* __restrict__ cnt,
                                                unsigned* __restrict__ totals) {
    __shared__ unsigned buf[2][512];
    int k = blockIdx.x, t = threadIdx.x;
    unsigned v = cnt[(size_t)t * NBUCK + k];
    buf[0][t] = v;
    __syncthreads();
    int cur = 0;
    for (int off = 1; off < 512; off <<= 1) {
        unsigned x = buf[cur][t];
        if (t >= off) x += buf[cur][t - off];
        buf[cur ^ 1][t] = x;
        cur ^= 1;
        __syncthreads();
    }
    cnt[(size_t)t * NBUCK + k] = buf[cur][t] - v;  // exclusive over blocks
    if (t == 511) totals[k] = buf[cur][511];
}

// exclusive scan of bucket totals -> start[0..NBUCK] (start[NBUCK] = E)
__global__ __launch_bounds__(1024) void total_scan(const unsigned* __restrict__ totals,
                                                   unsigned* __restrict__ start) {
    __shared__ unsigned buf[2][1024];
    int t = threadIdx.x;
    buf[0][t] = (t < NBUCK) ? totals[t] : 0;
    __syncthreads();
    int cur = 0;
    for (int off = 1; off < 1024; off <<= 1) {
        unsigned x = buf[cur][t];
        if (t >= off) x += buf[cur][t - off];
        buf[cur ^ 1][t] = x;
        cur ^= 1;
        __syncthreads();
    }
    if (t < NBUCK) start[t + 1] = buf[cur][t];
    if (t == 0) start[0] = 0;
}

// scatter edges into bucket-partitioned layout; slots disjoint by construction
__global__ __launch_bounds__(256) void part_scatter(const int* __restrict__ src,
                                                    const int* __restrict__ dst, int E,
                                                    const unsigned* __restrict__ cntD,
                                                    const unsigned* __restrict__ cntS,
                                                    const unsigned* __restrict__ startD,
                                                    const unsigned* __restrict__ startS,
                                                    unsigned* __restrict__ pairD,
                                                    unsigned* __restrict__ valS) {
    __shared__ unsigned curD[NBUCK], curS[NBUCK];
    for (int i = threadIdx.x; i < NBUCK; i += 256) { curD[i] = 0; curS[i] = 0; }
    __syncthreads();
    int chunk = (E + NBLK - 1) / NBLK;
    int e0 = blockIdx.x * chunk, e1 = min(E, e0 + chunk);
    const unsigned* bd = cntD + (size_t)blockIdx.x * NBUCK;
    const unsigned* bs = cntS + (size_t)blockIdx.x * NBUCK;
    for (int e = e0 + threadIdx.x; e < e1; e += 256) {
        unsigned s = (unsigned)src[e], d = (unsigned)dst[e];
        unsigned kd = d >> 7, ks = s >> 7;
        unsigned rd = atomicAdd(&curD[kd], 1u);                 // LDS rank
        pairD[startD[kd] + bd[kd] + rd] = s | ((d & 127u) << 17);
        unsigned rs = atomicAdd(&curS[ks], 1u);
        valS[startS[ks] + bs[ks] + rs] = s & 127u;
    }
}

// ---------------- phase B: per-bucket counting sort -> full CSR (no global atomics) ----------

__global__ __launch_bounds__(256) void bucket_sort(const unsigned* __restrict__ pairD,
                                                   const unsigned* __restrict__ startD,
                                                   int* __restrict__ col, int* __restrict__ row_ptr,
                                                   int* __restrict__ deg_arr,
                                                   float* __restrict__ norm_in, int n) {
    __shared__ unsigned cnt[BN];
    __shared__ unsigned base[BN];
    __shared__ unsigned sbuf[2][BN];
    int t = threadIdx.x;
    if (t < BN) cnt[t] = 0;
    __syncthreads();
    int k = blockIdx.x;
    unsigned a0 = startD[k], a1 = startD[k + 1];
    for (unsigned i = a0 + t; i < a1; i += 256)
        atomicAdd(&cnt[(pairD[i] >> 17) & 127u], 1u);
    __syncthreads();
    unsigned v = (t < BN) ? cnt[t] : 0;
    if (t < BN) sbuf[0][t] = v;
    __syncthreads();
    int cur = 0;
    for (int off = 1; off < BN; off <<= 1) {
        if (t < BN) {
            unsigned x = sbuf[cur][t];
            if (t >= off) x += sbuf[cur][t - off];
            sbuf[cur ^ 1][t] = x;
        }
        cur ^= 1;
        __syncthreads();
    }
    if (t < BN) {
        base[t] = a0 + sbuf[cur][t] - v;  // exclusive within bucket
        int node = k * BN + t;
        if (node < n) {
            row_ptr[node] = (int)base[t];
            deg_arr[node] = (int)v;
            norm_in[node] = rsqrtf((float)(v > 1u ? v : 1u));
        }
        cnt[t] = 0;  // reuse as cursor
    }
    __syncthreads();
    for (unsigned i = a0 + t; i < a1; i += 256) {
        unsigned pv = pairD[i];
        unsigned l = (pv >> 17) & 127u;
        unsigned r = atomicAdd(&cnt[l], 1u);   // LDS rank
        col[base[l] + r] = (int)(pv & 0x1FFFFu);
    }
}

// src-side degree -> norm_out
__global__ __launch_bounds__(256) void bucket_norms_src(const unsigned* __restrict__ valS,
                                                        const unsigned* __restrict__ startS,
                                                        float* __restrict__ norm_out, int n) {
    __shared__ unsigned cnt[BN];
    if (threadIdx.x < BN) cnt[threadIdx.x] = 0;
    __syncthreads();
    int k = blockIdx.x;
    unsigned a0 = startS[k], a1 = startS[k + 1];
    for (unsigned i = a0 + threadIdx.x; i < a1; i += 256)
        atomicAdd(&cnt[valS[i]], 1u);
    __syncthreads();
    if (threadIdx.x < BN) {
        int node = k * BN + threadIdx.x;
        if (node < n) {
            unsigned c = cnt[threadIdx.x];
            norm_out[node] = rsqrtf((float)(c > 1u ? c : 1u));
        }
    }
}

// ---------------- layer-1 projection with norm_out prescale ----------------

__global__ void gemm1_kernel(const float* __restrict__ x, const float* __restrict__ W,
                             const float* __restrict__ norm_out, float* __restrict__ h, int n) {
    __shared__ float Wl[F_IN * F_HID];  // 16 KB
    for (int i = threadIdx.x; i < F_IN * F_HID; i += blockDim.x) Wl[i] = W[i];
    __syncthreads();
    int node = blockIdx.x * blockDim.x + threadIdx.x;
    if (node >= n) return;
    float acc[F_HID];
#pragma unroll
    for (int j = 0; j < F_HID; ++j) acc[j] = 0.f;
    const float4* row = reinterpret_cast<const float4*>(x + (size_t)node * F_IN);
#pragma unroll 2
    for (int k4 = 0; k4 < F_IN / 4; ++k4) {
        float4 v = row[k4];
        const float* w0 = &Wl[(k4 * 4 + 0) * F_HID];
        const float* w1 = &Wl[(k4 * 4 + 1) * F_HID];
        const float* w2 = &Wl[(k4 * 4 + 2) * F_HID];
        const float* w3 = &Wl[(k4 * 4 + 3) * F_HID];
#pragma unroll
        for (int j = 0; j < F_HID; ++j)
            acc[j] += v.x * w0[j] + v.y * w1[j] + v.z * w2[j] + v.w * w3[j];
    }
    float s = norm_out[node];
    float* out = h + (size_t)node * F_HID;
#pragma unroll
    for (int j = 0; j < F_HID; ++j) out[j] = acc[j] * s;
}

// ---------------- gather aggregation: 8 lanes/node, float4/lane, 8-edge unroll --------------

__device__ __forceinline__ float4 shfl4_8(float4 v, int sl) {
    float4 r;
    r.x = __shfl(v.x, sl, 8);
    r.y = __shfl(v.y, sl, 8);
    r.z = __shfl(v.z, sl, 8);
    r.w = __shfl(v.w, sl, 8);
    return r;
}

// layer 1: agg + norm_in + b1 + relu, GEMM2 (8-lane shfl), prescale norm_out -> h2s
__global__ __launch_bounds__(256) void agg1_kernel(const float* __restrict__ h1s,
                                                   const int* __restrict__ row_ptr,
                                                   const int* __restrict__ deg_arr,
                                                   const int* __restrict__ col,
                                                   const float* __restrict__ norm_in,
                                                   const float* __restrict__ norm_out,
                                                   const float* __restrict__ b1,
                                                   const float* __restrict__ W2,
                                                   float* __restrict__ h2s, int n) {
    __shared__ float W2l[F_HID * F_HID];  // row k holds W2[k][0..31]
    for (int i = threadIdx.x; i < F_HID * F_HID; i += 256) W2l[i] = W2[i];
    __syncthreads();
    const float4* h4 = reinterpret_cast<const float4*>(h1s);
    const float4* W24 = reinterpret_cast<const float4*>(W2l);
    int q = threadIdx.x & 7;                 // lane in 8-lane group
    int node = blockIdx.x * 32 + (threadIdx.x >> 3);
    if (node >= n) return;
    int start = row_ptr[node];
    int deg = deg_arr[node];
    float4 acc = make_float4(0.f, 0.f, 0.f, 0.f);
    int jj = 0;
    for (; jj + 8 <= deg; jj += 8) {
        int c = col[start + jj + q];         // 8 lanes: one coalesced 32B load
#pragma unroll
        for (int m = 0; m < 8; ++m) {
            int s = __shfl(c, m, 8);
            float4 v = h4[(size_t)s * 8 + q];
            acc.x += v.x; acc.y += v.y; acc.z += v.z; acc.w += v.w;
        }
    }
    int rem = deg - jj;
    if (rem > 0) {
        int c = col[start + jj + (q < rem ? q : 0)];
        for (int m = 0; m < rem; ++m) {
            int s = __shfl(c, m, 8);
            float4 v = h4[(size_t)s * 8 + q];
            acc.x += v.x; acc.y += v.y; acc.z += v.z; acc.w += v.w;
        }
    }
    float ni = norm_in[node];
    const float4 b14 = reinterpret_cast<const float4*>(b1)[q];
    float4 t;
    t.x = fmaxf(acc.x * ni + b14.x, 0.f);
    t.y = fmaxf(acc.y * ni + b14.y, 0.f);
    t.z = fmaxf(acc.z * ni + b14.z, 0.f);
    t.w = fmaxf(acc.w * ni + b14.w, 0.f);
    // GEMM2: o[f] = sum_k t[k] * W2[k][f]; t distributed 4-per-lane over 8 lanes
    float4 o = make_float4(0.f, 0.f, 0.f, 0.f);
#pragma unroll
    for (int sl = 0; sl < 8; ++sl) {
        float4 tt = shfl4_8(t, sl);
        int kb = sl * 4;
        float4 w0 = W24[(kb + 0) * 8 + q];
        float4 w1 = W24[(kb + 1) * 8 + q];
        float4 w2 = W24[(kb + 2) * 8 + q];
        float4 w3 = W24[(kb + 3) * 8 + q];
        o.x += tt.x * w0.x + tt.y * w1.x + tt.z * w2.x + tt.w * w3.x;
        o.y += tt.x * w0.y + tt.y * w1.y + tt.z * w2.y + tt.w * w3.y;
        o.z += tt.x * w0.z + tt.y * w1.z + tt.z * w2.z + tt.w * w3.z;
        o.w += tt.x * w0.w + tt.y * w1.w + tt.z * w2.w + tt.w * w3.w;
    }
    float no = norm_out[node];
    o.x *= no; o.y *= no; o.z *= no; o.w *= no;
    reinterpret_cast<float4*>(h2s)[(size_t)node * 8 + q] = o;
}

// layer 2: agg + norm_in + b2 -> out
__global__ __launch_bounds__(256) void agg2_kernel(const float* __restrict__ h2s,
                                                   const int* __restrict__ row_ptr,
                                                   const int* __restrict__ deg_arr,
                                                   const int* __restrict__ col,
                                                   const float* __restrict__ norm_in,
                                                   const float* __restrict__ b2,
                                                   float* __restrict__ out, int n) {
    const float4* h4 = reinterpret_cast<const float4*>(h2s);
    int q = threadIdx.x & 7;
    int node = blockIdx.x * 32 + (threadIdx.x >> 3);
    if (node >= n) return;
    int start = row_ptr[node];
    int deg = deg_arr[node];
    float4 acc = make_float4(0.f, 0.f, 0.f, 0.f);
    int jj = 0;
    for (; jj + 8 <= deg; jj += 8) {
        int c = col[start + jj + q];
#pragma unroll
        for (int m = 0; m < 8; ++m) {
            int s = __shfl(c, m, 8);
            float4 v = h4[(size_t)s * 8 + q];
            acc.x += v.x; acc.y += v.y; acc.z += v.z; acc.w += v.w;
        }
    }
    int rem = deg - jj;
    if (rem > 0) {
        int c = col[start + jj + (q < rem ? q : 0)];
        for (int m = 0; m < rem; ++m) {
            int s = __shfl(c, m, 8);
            float4 v = h4[(size_t)s * 8 + q];
            acc.x += v.x; acc.y += v.y; acc.z += v.z; acc.w += v.w;
        }
    }
    float ni = norm_in[node];
    const float4 b24 = reinterpret_cast<const float4*>(b2)[q];
    float4 o;
    o.x = acc.x * ni + b24.x;
    o.y = acc.y * ni + b24.y;
    o.z = acc.z * ni + b24.z;
    o.w = acc.w * ni + b24.w;
    reinterpret_cast<float4*>(out)[(size_t)node * 8 + q] = o;
}

// ---------------- launch ----------------

static inline size_t align256(size_t x) { return (x + 255) & ~(size_t)255; }

extern "C" void kernel_launch(void* const* d_in, const int* in_sizes, int n_in,
                              void* d_out, int out_size, void* d_ws, size_t ws_size,
                              hipStream_t stream) {
    const float* features = (const float*)d_in[0];
    const float* W1 = (const float*)d_in[1];
    const float* b1 = (const float*)d_in[2];
    const float* W2 = (const float*)d_in[3];
    const float* b2 = (const float*)d_in[4];
    const int* src = (const int*)d_in[5];
    const int* dst = (const int*)d_in[6];
    const int E = in_sizes[5];
    const int n = N_NODES;
    float* out = (float*)d_out;

    char* ws = (char*)d_ws;
    size_t off = 0;
    float* norm_out = (float*)(ws + off); off += align256((size_t)n * 4);
    float* norm_in = (float*)(ws + off);  off += align256((size_t)n * 4);
    int* row_ptr = (int*)(ws + off);      off += align256((size_t)n * 4);
    int* deg_arr = (int*)(ws + off);      off += align256((size_t)n * 4);
    unsigned* startD = (unsigned*)(ws + off); off += align256((NBUCK + 1) * 4);
    unsigned* startS = (unsigned*)(ws + off); off += align256((NBUCK + 1) * 4);
    unsigned* totD = (unsigned*)(ws + off);   off += align256(NBUCK * 4);
    unsigned* totS = (unsigned*)(ws + off);   off += align256(NBUCK * 4);
    int* col = (int*)(ws + off);              off += align256((size_t)E * 4);  // 6.4 MB

    // region X: pairD+valS (live: part_scatter -> bucket kernels) then h2s (live: agg1 -> agg2)
    size_t regX = off;
    unsigned* pairD = (unsigned*)(ws + regX);                        // 6.4 MB
    unsigned* valS = (unsigned*)(ws + regX + (size_t)E * 4);         // 6.4 MB
    float* h2s = (float*)(ws + regX);                                // 12.8 MB
    off += align256((size_t)2 * E * 4);
    // region Y: cntD+cntS (live: part_count -> part_scatter) then h1s (live: gemm1 -> agg1)
    size_t regY = off;
    unsigned* cntD = (unsigned*)(ws + regY);                         // 1.6 MB
    unsigned* cntS = (unsigned*)(ws + regY + (size_t)NBLK * NBUCK * 4);
    float* h1s = (float*)(ws + regY);                                // 12.8 MB

    // phase A: partition edges by dst-bucket (pairs) and src-bucket (locals)
    part_count<<<NBLK, 256, 0, stream>>>(src, dst, E, cntD, cntS);
    col_scan<<<NBUCK, 512, 0, stream>>>(cntD, totD);
    col_scan<<<NBUCK, 512, 0, stream>>>(cntS, totS);
    total_scan<<<1, 1024, 0, stream>>>(totD, startD);
    total_scan<<<1, 1024, 0, stream>>>(totS, startS);
    part_scatter<<<NBLK, 256, 0, stream>>>(src, dst, E, cntD, cntS, startD, startS, pairD, valS);

    // phase B: per-bucket counting sort -> CSR (+ norm_in), src norms
    bucket_sort<<<NBUCK, 256, 0, stream>>>(pairD, startD, col, row_ptr, deg_arr, norm_in, n);
    bucket_norms_src<<<NBUCK, 256, 0, stream>>>(valS, startS, norm_out, n);

    // layer 1 projection (+ norm_out prescale)
    gemm1_kernel<<<(n + 255) / 256, 256, 0, stream>>>(features, W1, norm_out, h1s, n);

    // gather aggregation (8 lanes/node, float4), fused epilogues
    agg1_kernel<<<(n + 31) / 32, 256, 0, stream>>>(h1s, row_ptr, deg_arr, col, norm_in,
                                                   norm_out, b1, W2, h2s, n);
    agg2_kernel<<<(n + 31) / 32, 256, 0, stream>>>(h2s, row_ptr, deg_arr, col, norm_in, b2, out, n);
}